// Round 5
// baseline (1285.109 us; speedup 1.0000x reference)
//
#include <hip/hip_runtime.h>

#define NN 512
#define DD 64
#define BB 64
#define ND (NN * DD)          // 32768

typedef __bf16 bf16x8 __attribute__((ext_vector_type(8)));
typedef float  f32x4  __attribute__((ext_vector_type(4)));

// fp32 -> bf16 round-to-nearest-even
__device__ __forceinline__ unsigned short f2bf(float x) {
    unsigned int u = __float_as_uint(x);
    unsigned int r = u + 0x7fffu + ((u >> 16) & 1u);
    return (unsigned short)(r >> 16);
}
__device__ __forceinline__ float bf2f(unsigned short u) {
    return __uint_as_float(((unsigned int)u) << 16);
}
// packed: hi bf16 in low 16 bits, lo bf16 in high 16 bits (x ~= hi + lo)
__device__ __forceinline__ unsigned int packf(float x) {
    unsigned short hi = f2bf(x);
    unsigned short lo = f2bf(x - bf2f(hi));
    return (unsigned int)hi | ((unsigned int)lo << 16);
}
__device__ __forceinline__ float unpackf(unsigned int p) {
    return __uint_as_float(p << 16) + __uint_as_float(p & 0xffff0000u);
}
__device__ __forceinline__ void pack4(const float4& v, uint4& P) {
    P.x = packf(v.x); P.y = packf(v.y); P.z = packf(v.z); P.w = packf(v.w);
}
__device__ __forceinline__ void cvt4(const float4& x, ushort4& h, ushort4& l) {
    float xs[4] = {x.x, x.y, x.z, x.w};
    unsigned short hh[4], ll[4];
#pragma unroll
    for (int i = 0; i < 4; ++i) {
        hh[i] = f2bf(xs[i]);
        ll[i] = f2bf(xs[i] - bf2f(hh[i]));
    }
    h = make_ushort4(hh[0], hh[1], hh[2], hh[3]);
    l = make_ushort4(ll[0], ll[1], ll[2], ll[3]);
}
__device__ __forceinline__ bf16x8 ld_bf8(const unsigned short* p) {
    int4 v = *reinterpret_cast<const int4*>(p);
    return __builtin_bit_cast(bf16x8, v);
}
// de-interleave 8 packed words -> hi frag + lo frag (6 shift/or per 2 elems)
__device__ __forceinline__ void unpack8(const int4& u0, const int4& u1,
                                        bf16x8& h8, bf16x8& l8) {
    const unsigned int* a = reinterpret_cast<const unsigned int*>(&u0);
    const unsigned int* b = reinterpret_cast<const unsigned int*>(&u1);
    int4 hv, lv;
    unsigned int* hw = reinterpret_cast<unsigned int*>(&hv);
    unsigned int* lw = reinterpret_cast<unsigned int*>(&lv);
    hw[0] = (a[0] & 0xffffu) | (a[1] << 16);
    lw[0] = (a[0] >> 16) | (a[1] & 0xffff0000u);
    hw[1] = (a[2] & 0xffffu) | (a[3] << 16);
    lw[1] = (a[2] >> 16) | (a[3] & 0xffff0000u);
    hw[2] = (b[0] & 0xffffu) | (b[1] << 16);
    lw[2] = (b[0] >> 16) | (b[1] & 0xffff0000u);
    hw[3] = (b[2] & 0xffffu) | (b[3] << 16);
    lw[3] = (b[2] >> 16) | (b[3] & 0xffff0000u);
    h8 = __builtin_bit_cast(bf16x8, hv);
    l8 = __builtin_bit_cast(bf16x8, lv);
}
__device__ __forceinline__ f32x4 mfma16(bf16x8 a, bf16x8 b, f32x4 c) {
    return __builtin_amdgcn_mfma_f32_16x16x32_bf16(a, b, c, 0, 0, 0);
}
// short-plane LDS tile [64r][64 shorts], XOR swizzle on 8-short octets (R2-proven)
__device__ __forceinline__ int swzW4(int r, int c) {   // c = ushort4 group 0..15
    return r * 64 + (((c >> 1) ^ (r & 7)) << 3) + ((c & 1) << 2);
}
__device__ __forceinline__ int swzR(int r, int oct) {  // oct 0..7
    return r * 64 + ((oct ^ (r & 7)) << 3);
}
// packed LDS tile [64r][64 uint32], XOR swizzle on uint4 groups (16 per row)
__device__ __forceinline__ int swzP(int r, int g) {    // g 0..15
    return r * 64 + ((g ^ (r & 15)) << 2);
}

// ---------------------------------------------------------------------------
// MFMA GEMM v5: out[b,z,i,f] = alpha*sum_k A[b,i,k]*B[(b,z),f,k] (+beta*Vm)(+Zt)(+bias)
// AMODE 0: A fp32 row-major -> cvt-split into LDS planes (fallback, R2-proven).
// AMODE 2: A hi/lo short planes row-major -> LDS plane copy (zero VALU).
// AMODE 3: A packed uint32 row-major -> LDS packed copy, unpack at frag read.
// B: packed uint32 [.., f, kdim], LDS packed copy, unpack at frag read.
// Vm/Zt: packed col-major [b][64f][512n]. OUTF 0: packed col-major (uint4,
// full-line); 1: fp32 col-major; 2: packed row-major [n][64] (4B x 16 lanes
// = full line). 3-term split MFMA ~ fp32 precision.
// ---------------------------------------------------------------------------
template <int AMODE, bool HAS_VM, bool HAS_Z, bool HAS_BIAS, int OUTF>
__global__ __launch_bounds__(256) void gemm_v5(
    const float* __restrict__ Afp,
    const unsigned short* __restrict__ Ah, const unsigned short* __restrict__ Al,
    const unsigned int* __restrict__ Ap, int lda, long aBatch,
    const unsigned int* __restrict__ Bp, long bBatch, long bZ,
    const unsigned int* __restrict__ Vm, const unsigned int* __restrict__ Zt,
    const float* __restrict__ bias, float alpha, float beta, int kdim,
    unsigned int* __restrict__ outP, float* __restrict__ outF, long outZ)
{
    const int b = blockIdx.y, z = blockIdx.z;
    const int i0 = blockIdx.x * 64;
    const long aOff = (long)b * aBatch;
    const long bOff = (long)b * bBatch + (long)z * bZ;

    __shared__ __align__(16) unsigned char smem[32768];
    unsigned short* sAh = (unsigned short*)smem;            // 8KB (AMODE 0/2)
    unsigned short* sAl = (unsigned short*)(smem + 8192);   // 8KB
    unsigned int*   sAp = (unsigned int*)smem;              // 16KB (AMODE 3)
    unsigned int*   sBp = (unsigned int*)(smem + 16384);    // 16KB

    const int t = threadIdx.x;
    const int w = t >> 6, lane = t & 63;
    const int wr = w >> 1, wc = w & 1;
    const int lr = lane & 15, lg = lane >> 4;

    f32x4 acc[2][2];
#pragma unroll
    for (int m = 0; m < 2; ++m)
#pragma unroll
        for (int n = 0; n < 2; ++n) acc[m][n] = f32x4{0.f, 0.f, 0.f, 0.f};

    const int steps = kdim >> 6;

    float4 ra[4];                 // AMODE 0
    int4 pah[2], pal[2];          // AMODE 2
    int4 pap[4];                  // AMODE 3
    int4 pb[4];                   // B packed

    auto prefA = [&](int k0) {
        if (AMODE == 0) {
#pragma unroll
            for (int l = 0; l < 4; ++l) {
                int q = t + l * 256, r = q >> 4, c = q & 15;
                ra[l] = *reinterpret_cast<const float4*>(Afp + aOff + (long)(i0 + r) * lda + k0 + c * 4);
            }
        } else if (AMODE == 2) {
#pragma unroll
            for (int l = 0; l < 2; ++l) {
                int q = t + l * 256, r = q >> 3, oct = q & 7;
                long g = aOff + (long)(i0 + r) * lda + k0 + oct * 8;
                pah[l] = *reinterpret_cast<const int4*>(Ah + g);
                pal[l] = *reinterpret_cast<const int4*>(Al + g);
            }
        } else {
#pragma unroll
            for (int l = 0; l < 4; ++l) {
                int q = t + l * 256, r = q >> 4, gg = q & 15;
                pap[l] = *reinterpret_cast<const int4*>(Ap + aOff + (long)(i0 + r) * lda + k0 + gg * 4);
            }
        }
    };
    auto prefB = [&](int k0) {
#pragma unroll
        for (int l = 0; l < 4; ++l) {
            int q = t + l * 256, r = q >> 4, gg = q & 15;
            pb[l] = *reinterpret_cast<const int4*>(Bp + bOff + (long)r * kdim + k0 + gg * 4);
        }
    };

    prefA(0);
    prefB(0);

    for (int s = 0; s < steps; ++s) {
        if (s) __syncthreads();
        // ---- stage to LDS ----
        if (AMODE == 0) {
#pragma unroll
            for (int l = 0; l < 4; ++l) {
                int q = t + l * 256, r = q >> 4, c = q & 15;
                int idx = swzW4(r, c);
                ushort4 h4, l4;
                cvt4(ra[l], h4, l4);
                *reinterpret_cast<ushort4*>(&sAh[idx]) = h4;
                *reinterpret_cast<ushort4*>(&sAl[idx]) = l4;
            }
        } else if (AMODE == 2) {
#pragma unroll
            for (int l = 0; l < 2; ++l) {
                int q = t + l * 256, r = q >> 3, oct = q & 7;
                int idx = r * 64 + ((oct ^ (r & 7)) << 3);
                *reinterpret_cast<int4*>(&sAh[idx]) = pah[l];
                *reinterpret_cast<int4*>(&sAl[idx]) = pal[l];
            }
        } else {
#pragma unroll
            for (int l = 0; l < 4; ++l) {
                int q = t + l * 256, r = q >> 4, gg = q & 15;
                *reinterpret_cast<int4*>(&sAp[swzP(r, gg)]) = pap[l];
            }
        }
#pragma unroll
        for (int l = 0; l < 4; ++l) {
            int q = t + l * 256, r = q >> 4, gg = q & 15;
            *reinterpret_cast<int4*>(&sBp[swzP(r, gg)]) = pb[l];
        }
        __syncthreads();
        if (s + 1 < steps) {
            prefA((s + 1) << 6);
            prefB((s + 1) << 6);
        }
        // ---- MFMA ----
#pragma unroll
        for (int c2 = 0; c2 < 2; ++c2) {
            const int oct = c2 * 4 + lg;
            bf16x8 a_h[2], a_l[2], b_h[2], b_l[2];
#pragma unroll
            for (int m = 0; m < 2; ++m) {
                int row = wr * 32 + m * 16 + lr;
                if (AMODE == 3) {
                    int g0 = oct * 2;
                    int4 u0 = *reinterpret_cast<const int4*>(&sAp[swzP(row, g0)]);
                    int4 u1 = *reinterpret_cast<const int4*>(&sAp[swzP(row, g0 + 1)]);
                    unpack8(u0, u1, a_h[m], a_l[m]);
                } else {
                    int ai = swzR(row, oct);
                    a_h[m] = ld_bf8(&sAh[ai]);
                    a_l[m] = ld_bf8(&sAl[ai]);
                }
                int col = wc * 32 + m * 16 + lr;
                int g0 = oct * 2;
                int4 v0 = *reinterpret_cast<const int4*>(&sBp[swzP(col, g0)]);
                int4 v1 = *reinterpret_cast<const int4*>(&sBp[swzP(col, g0 + 1)]);
                unpack8(v0, v1, b_h[m], b_l[m]);
            }
#pragma unroll
            for (int m = 0; m < 2; ++m)
#pragma unroll
                for (int n = 0; n < 2; ++n) {
                    acc[m][n] = mfma16(a_h[m], b_h[n], acc[m][n]);
                    acc[m][n] = mfma16(a_h[m], b_l[n], acc[m][n]);
                    acc[m][n] = mfma16(a_l[m], b_h[n], acc[m][n]);
                }
        }
    }

    // epilogue: C/D frag: col = lane&15, row = (lane>>4)*4 + reg (verified)
    const long cOff = (long)b * ND;
    const long oOff = (long)z * outZ + cOff;
#pragma unroll
    for (int m = 0; m < 2; ++m) {
        const int nb = i0 + wr * 32 + m * 16 + lg * 4;
#pragma unroll
        for (int n = 0; n < 2; ++n) {
            const int f = wc * 32 + n * 16 + lr;
            float4 v;
            v.x = alpha * acc[m][n][0]; v.y = alpha * acc[m][n][1];
            v.z = alpha * acc[m][n][2]; v.w = alpha * acc[m][n][3];
            if (HAS_VM) {
                uint4 mp = *reinterpret_cast<const uint4*>(Vm + cOff + (long)f * NN + nb);
                v.x += beta * unpackf(mp.x); v.y += beta * unpackf(mp.y);
                v.z += beta * unpackf(mp.z); v.w += beta * unpackf(mp.w);
            }
            if (HAS_Z) {
                uint4 zp = *reinterpret_cast<const uint4*>(Zt + cOff + (long)f * NN + nb);
                v.x += unpackf(zp.x); v.y += unpackf(zp.y);
                v.z += unpackf(zp.z); v.w += unpackf(zp.w);
            }
            if (HAS_BIAS) {
                float bf = bias[f];
                v.x += bf; v.y += bf; v.z += bf; v.w += bf;
            }
            if (OUTF == 0) {
                uint4 P; pack4(v, P);
                *reinterpret_cast<uint4*>(outP + oOff + (long)f * NN + nb) = P;
            } else if (OUTF == 1) {
                *reinterpret_cast<float4*>(outF + cOff + (long)f * NN + nb) = v;
            } else {
                float vs[4] = {v.x, v.y, v.z, v.w};
#pragma unroll
                for (int jj = 0; jj < 4; ++jj)
                    outP[cOff + (long)(nb + jj) * DD + f] = packf(vs[jj]);
            }
        }
    }
}

// ---------------------------------------------------------------------------
// fp32 -> hi/lo short planes (layout preserved) — for the A operand (gso / X)
// ---------------------------------------------------------------------------
__global__ __launch_bounds__(256) void split_planes(
    const float* __restrict__ in, unsigned short* __restrict__ oh,
    unsigned short* __restrict__ ol, long n4)
{
    long i = (long)blockIdx.x * 256 + threadIdx.x;
    const long stride = (long)gridDim.x * 256;
    for (; i < n4; i += stride) {
        float4 v = reinterpret_cast<const float4*>(in)[i];
        ushort4 h4, l4;
        cvt4(v, h4, l4);
        reinterpret_cast<ushort4*>(oh)[i] = h4;
        reinterpret_cast<ushort4*>(ol)[i] = l4;
    }
}

// ---------------------------------------------------------------------------
// AE[b,i,j] = relu(dot(X0[b,i,:], X0[b,j,:])), diag zeroed.
// X0 packed row-major [512][64]; register-direct contiguous 32B reads.
// ---------------------------------------------------------------------------
__global__ __launch_bounds__(256) void outer_v5(
    const unsigned int* __restrict__ X0p, float* __restrict__ AE)
{
    const int b = blockIdx.z;
    const int j0 = blockIdx.x * 64, i0 = blockIdx.y * 64;
    const long xb = (long)b * ND;

    const int t = threadIdx.x;
    const int w = t >> 6, lane = t & 63;
    const int wr = w >> 1, wc = w & 1;
    const int lr = lane & 15, lg = lane >> 4;

    f32x4 acc[2][2];
#pragma unroll
    for (int m = 0; m < 2; ++m)
#pragma unroll
        for (int n = 0; n < 2; ++n) acc[m][n] = f32x4{0.f, 0.f, 0.f, 0.f};

#pragma unroll
    for (int c2 = 0; c2 < 2; ++c2) {
        const int oct = c2 * 4 + lg;
        bf16x8 a_h[2], a_l[2], b_h[2], b_l[2];
#pragma unroll
        for (int m = 0; m < 2; ++m) {
            long ga = xb + (long)(i0 + wr * 32 + m * 16 + lr) * DD + oct * 8;
            int4 u0 = *reinterpret_cast<const int4*>(X0p + ga);
            int4 u1 = *reinterpret_cast<const int4*>(X0p + ga + 4);
            unpack8(u0, u1, a_h[m], a_l[m]);
            long gb = xb + (long)(j0 + wc * 32 + m * 16 + lr) * DD + oct * 8;
            int4 v0 = *reinterpret_cast<const int4*>(X0p + gb);
            int4 v1 = *reinterpret_cast<const int4*>(X0p + gb + 4);
            unpack8(v0, v1, b_h[m], b_l[m]);
        }
#pragma unroll
        for (int m = 0; m < 2; ++m)
#pragma unroll
            for (int n = 0; n < 2; ++n) {
                acc[m][n] = mfma16(a_h[m], b_h[n], acc[m][n]);
                acc[m][n] = mfma16(a_h[m], b_l[n], acc[m][n]);
                acc[m][n] = mfma16(a_l[m], b_h[n], acc[m][n]);
            }
    }

    float* __restrict__ AEb = AE + (long)b * NN * NN;
#pragma unroll
    for (int m = 0; m < 2; ++m) {
        const int ib = i0 + wr * 32 + m * 16 + lg * 4;
#pragma unroll
        for (int n = 0; n < 2; ++n) {
            const int jc = j0 + wc * 32 + n * 16 + lr;
#pragma unroll
            for (int jj = 0; jj < 4; ++jj) {
                float v = fmaxf(acc[m][n][jj], 0.f);
                if (ib + jj == jc) v = 0.f;
                AEb[(long)(ib + jj) * NN + jc] = v;
            }
        }
    }
}

// ---------------------------------------------------------------------------
// LayerNorm over [N,D] + relu + mean/max pool. pre: fp32 col-major [64][512].
// h out: packed row-major [512][64] (uint4 = 16B/lane, full-line).
// ---------------------------------------------------------------------------
__global__ __launch_bounds__(256) void ln_pool(
    const float* __restrict__ pre, const float* __restrict__ gamma,
    const float* __restrict__ beta,
    unsigned int* __restrict__ hp, float* __restrict__ zfeat, int zoff)
{
    const int b = blockIdx.x;
    const float* __restrict__ p = pre + (long)b * ND;
    const int t = threadIdx.x;

    float s = 0.f, s2 = 0.f;
    for (int i = t * 4; i < ND; i += 1024) {
        float4 v = *reinterpret_cast<const float4*>(p + i);
        s  += v.x + v.y + v.z + v.w;
        s2 += v.x * v.x + v.y * v.y + v.z * v.z + v.w * v.w;
    }
#pragma unroll
    for (int off = 32; off > 0; off >>= 1) {
        s  += __shfl_down(s, off, 64);
        s2 += __shfl_down(s2, off, 64);
    }
    __shared__ float red[8];
    if ((t & 63) == 0) { red[(t >> 6) * 2] = s; red[(t >> 6) * 2 + 1] = s2; }
    __syncthreads();
    __shared__ float mu_s, rstd_s;
    if (t == 0) {
        float ts  = red[0] + red[2] + red[4] + red[6];
        float ts2 = red[1] + red[3] + red[5] + red[7];
        float mu  = ts * (1.f / ND);
        float var = ts2 * (1.f / ND) - mu * mu;
        mu_s = mu; rstd_s = rsqrtf(var + 1e-5f);
    }
    __syncthreads();
    const float mu = mu_s, rstd = rstd_s;

    const int f4 = (t & 15) * 4, nt = t >> 4;
    float sum4[4] = {0.f, 0.f, 0.f, 0.f};
    float max4[4] = {0.f, 0.f, 0.f, 0.f};
    for (int n = nt; n < NN; n += 16) {
        float4 g4 = *reinterpret_cast<const float4*>(gamma + (long)n * DD + f4);
        float4 be = *reinterpret_cast<const float4*>(beta  + (long)n * DD + f4);
        float4 v;
        v.x = fmaxf((p[(long)(f4 + 0) * NN + n] - mu) * rstd * g4.x + be.x, 0.f);
        v.y = fmaxf((p[(long)(f4 + 1) * NN + n] - mu) * rstd * g4.y + be.y, 0.f);
        v.z = fmaxf((p[(long)(f4 + 2) * NN + n] - mu) * rstd * g4.z + be.z, 0.f);
        v.w = fmaxf((p[(long)(f4 + 3) * NN + n] - mu) * rstd * g4.w + be.w, 0.f);
        uint4 P; pack4(v, P);
        *reinterpret_cast<uint4*>(hp + (long)b * ND + (long)n * DD + f4) = P;
        sum4[0] += v.x; sum4[1] += v.y; sum4[2] += v.z; sum4[3] += v.w;
        max4[0] = fmaxf(max4[0], v.x); max4[1] = fmaxf(max4[1], v.y);
        max4[2] = fmaxf(max4[2], v.z); max4[3] = fmaxf(max4[3], v.w);
    }
    __shared__ float rs[16][64], rm[16][64];
#pragma unroll
    for (int j = 0; j < 4; ++j) { rs[nt][f4 + j] = sum4[j]; rm[nt][f4 + j] = max4[j]; }
    __syncthreads();
    if (t < 64) {
        float ss = 0.f, mm = 0.f;
#pragma unroll
        for (int k = 0; k < 16; ++k) { ss += rs[k][t]; mm = fmaxf(mm, rm[k][t]); }
        zfeat[b * 256 + zoff + t]      = ss * (1.f / NN);
        zfeat[b * 256 + zoff + 64 + t] = mm;
    }
}

// ---------------------------------------------------------------------------
// W[z][kdim][64] fp32 -> packed [z][64][kdim]
// ---------------------------------------------------------------------------
__global__ void transW_pack(const float* __restrict__ W,
                            unsigned int* __restrict__ Wp, int kdim, int total)
{
    int o = blockIdx.x * 256 + threadIdx.x;
    if (o >= total) return;
    int per = 64 * kdim;
    int zz = o / per, r = o % per;
    int f = r / kdim, k = r % kdim;
    Wp[o] = packf(W[((long)zz * kdim + k) * 64 + f]);
}

// ---------------------------------------------------------------------------
// Tiny MLP heads.
// ---------------------------------------------------------------------------
__global__ __launch_bounds__(64) void heads(
    const float* __restrict__ zfeat,
    const float* __restrict__ p1w, const float* __restrict__ p1b,
    const float* __restrict__ p2w, const float* __restrict__ p2b,
    const float* __restrict__ p3w, const float* __restrict__ p3b,
    const float* __restrict__ s1w, const float* __restrict__ s1b,
    const float* __restrict__ s2w, const float* __restrict__ s2b,
    const float* __restrict__ p4w, const float* __restrict__ p4b,
    float* __restrict__ outc, float* __restrict__ outs)
{
    const int b = blockIdx.x, t = threadIdx.x;
    __shared__ float zf[256], v1[64], v2[64], lg[2];
    for (int i = t; i < 256; i += 64) zf[i] = zfeat[b * 256 + i];
    __syncthreads();

    float a = p1b[t];
    for (int z = 0; z < 256; ++z) a = fmaf(zf[z], p1w[z * 64 + t], a);
    v1[t] = a >= 0.f ? a : 0.2f * a;
    __syncthreads();
    float a2 = p2b[t];
    for (int z = 0; z < 64; ++z) a2 = fmaf(v1[z], p2w[z * 64 + t], a2);
    v2[t] = a2 >= 0.f ? a2 : 0.2f * a2;
    __syncthreads();
    if (t < 4) {
        float a3 = p3b[t];
        for (int z = 0; z < 64; ++z) a3 = fmaf(v2[z], p3w[z * 4 + t], a3);
        outc[b * 4 + t] = 1.f / (1.f + expf(-a3));
    }
    __syncthreads();

    float c = s1b[t];
    for (int z = 0; z < 256; ++z) c = fmaf(zf[z], s1w[z * 64 + t], c);
    v1[t] = c >= 0.f ? c : 0.2f * c;
    __syncthreads();
    float c2 = s2b[t];
    for (int z = 0; z < 64; ++z) c2 = fmaf(v1[z], s2w[z * 64 + t], c2);
    v2[t] = c2 >= 0.f ? c2 : 0.2f * c2;
    __syncthreads();
    if (t < 2) {
        float d = p4b[t];
        for (int z = 0; z < 64; ++z) d = fmaf(v2[z], p4w[z * 2 + t], d);
        lg[t] = d;
    }
    __syncthreads();
    if (t < 2) {
        float m = fmaxf(lg[0], lg[1]);
        float lse = m + logf(expf(lg[0] - m) + expf(lg[1] - m));
        outs[b * 2 + t] = lg[t] - lse;
    }
}

// ---------------------------------------------------------------------------
// Clenshaw over in-place packed Z slots (col-major [b][64f][512n]).
// ---------------------------------------------------------------------------
static const long SLOTE = (long)BB * ND;

template <int AM>
static void chebRun(const float* A, const unsigned short* Ahp, const unsigned short* Alp,
                    unsigned int* Zp, const float* bias, int outf, float* Sbuf,
                    unsigned int* X0p, hipStream_t stream)
{
    const dim3 blk(256), grd(8, 64, 1);
    const long AB = (long)NN * NN;
    auto sP = [&](int k) { return Zp + k * SLOTE; };
    // g1: s4 = 2A*s5 + s4
    gemm_v5<AM, false, true, false, 0><<<grd, blk, 0, stream>>>(
        A, Ahp, Alp, nullptr, NN, AB, sP(5), (long)ND, 0L,
        nullptr, sP(4), nullptr, 2.f, 0.f, NN, sP(4), nullptr, 0L);
    // g2: s5 = 2A*s4 - s5 + s3
    gemm_v5<AM, true, true, false, 0><<<grd, blk, 0, stream>>>(
        A, Ahp, Alp, nullptr, NN, AB, sP(4), (long)ND, 0L,
        sP(5), sP(3), nullptr, 2.f, -1.f, NN, sP(5), nullptr, 0L);
    // g3: s4 = 2A*s5 - s4 + s2
    gemm_v5<AM, true, true, false, 0><<<grd, blk, 0, stream>>>(
        A, Ahp, Alp, nullptr, NN, AB, sP(5), (long)ND, 0L,
        sP(4), sP(2), nullptr, 2.f, -1.f, NN, sP(4), nullptr, 0L);
    // g4: s5 = 2A*s4 - s5 + s1
    gemm_v5<AM, true, true, false, 0><<<grd, blk, 0, stream>>>(
        A, Ahp, Alp, nullptr, NN, AB, sP(4), (long)ND, 0L,
        sP(5), sP(1), nullptr, 2.f, -1.f, NN, sP(5), nullptr, 0L);
    // g5: S = A*s5 - s4 + s0 + bias
    if (outf == 1)
        gemm_v5<AM, true, true, true, 1><<<grd, blk, 0, stream>>>(
            A, Ahp, Alp, nullptr, NN, AB, sP(5), (long)ND, 0L,
            sP(4), sP(0), bias, 1.f, -1.f, NN, nullptr, Sbuf, 0L);
    else
        gemm_v5<AM, true, true, true, 2><<<grd, blk, 0, stream>>>(
            A, Ahp, Alp, nullptr, NN, AB, sP(5), (long)ND, 0L,
            sP(4), sP(0), bias, 1.f, -1.f, NN, X0p, nullptr, 0L);
}

extern "C" void kernel_launch(void* const* d_in, const int* in_sizes, int n_in,
                              void* d_out, int out_size, void* d_ws, size_t ws_size,
                              hipStream_t stream)
{
    const float* A   = (const float*)d_in[0];
    const float* X   = (const float*)d_in[1];
    const float* W1  = (const float*)d_in[2];
    const float* b1v = (const float*)d_in[3];
    const float* W2  = (const float*)d_in[4];
    const float* b2v = (const float*)d_in[5];
    const float* W3  = (const float*)d_in[6];
    const float* b3v = (const float*)d_in[7];
    const float* g1  = (const float*)d_in[8];
    const float* bt1 = (const float*)d_in[9];
    const float* g2  = (const float*)d_in[10];
    const float* bt2 = (const float*)d_in[11];
    const float* p1w = (const float*)d_in[12];
    const float* p1b = (const float*)d_in[13];
    const float* p2w = (const float*)d_in[14];
    const float* p2b = (const float*)d_in[15];
    const float* p3w = (const float*)d_in[16];
    const float* p3b = (const float*)d_in[17];
    const float* s1w = (const float*)d_in[18];
    const float* s1b = (const float*)d_in[19];
    const float* s2w = (const float*)d_in[20];
    const float* s2b = (const float*)d_in[21];
    const float* p4w = (const float*)d_in[22];
    const float* p4b = (const float*)d_in[23];

    float* out = (float*)d_out;
    unsigned int* Zp = (unsigned int*)out;            // 6 packed slots, 50.3 MB
    float* Sbuf = out + 6 * SLOTE;                    // fp32, 50.3..58.7 MB (< 67.1)
    float* outc  = out + (long)BB * NN * NN;
    float* outsc = outc + BB * 4;

    // ws layout: hp | w1p | w2p | w3p | zfeat | Ah,Al planes | Xh,Xl planes
    unsigned int* wsp = (unsigned int*)d_ws;
    unsigned int* hp  = wsp;                          // packed h / X0 (aliased)
    unsigned int* X0p = hp;
    unsigned int* w1p = wsp + SLOTE;                  // 6*512*64
    unsigned int* w2p = w1p + 6 * NN * DD;            // 6*64*64
    unsigned int* w3p = w2p + 6 * DD * DD;
    float* zfeat = (float*)(w3p + 6 * DD * DD);
    unsigned short* Ahp = (unsigned short*)(zfeat + 16384);
    unsigned short* Alp = Ahp + (long)BB * NN * NN;
    unsigned short* Xhp = Alp + (long)BB * NN * NN;
    unsigned short* Xlp = Xhp + (long)BB * NN * NN;

    const bool splitA = ws_size >= 76546048ULL;       // base 9 MiB + A planes 64 MiB
    const bool splitX = ws_size >= 143654912ULL;      // + X planes 64 MiB

    const dim3 blk(256);
    const long AB = (long)NN * NN;

    transW_pack<<<dim3((6 * NN * DD + 255) / 256), blk, 0, stream>>>(W1, w1p, NN, 6 * NN * DD);
    transW_pack<<<dim3((6 * DD * DD + 255) / 256), blk, 0, stream>>>(W2, w2p, DD, 6 * DD * DD);
    transW_pack<<<dim3((6 * DD * DD + 255) / 256), blk, 0, stream>>>(W3, w3p, DD, 6 * DD * DD);
    if (splitA)
        split_planes<<<dim3(2048), blk, 0, stream>>>(A, Ahp, Alp, (long)BB * NN * NN / 4);
    if (splitX)
        split_planes<<<dim3(2048), blk, 0, stream>>>(X, Xhp, Xlp, (long)BB * NN * NN / 4);

    auto cheb = [&](const float* bias, int outf) {
        if (splitA) chebRun<2>(A, Ahp, Alp, Zp, bias, outf, Sbuf, X0p, stream);
        else        chebRun<0>(A, Ahp, Alp, Zp, bias, outf, Sbuf, X0p, stream);
    };

    // ---- stage 1: Z_k = X @ W1[k] ----
    if (splitX)
        gemm_v5<2, false, false, false, 0><<<dim3(8, 64, 6), blk, 0, stream>>>(
            nullptr, Xhp, Xlp, nullptr, NN, AB, w1p, 0L, (long)NN * DD,
            nullptr, nullptr, nullptr, 1.f, 0.f, NN, Zp, nullptr, SLOTE);
    else
        gemm_v5<0, false, false, false, 0><<<dim3(8, 64, 6), blk, 0, stream>>>(
            X, nullptr, nullptr, nullptr, NN, AB, w1p, 0L, (long)NN * DD,
            nullptr, nullptr, nullptr, 1.f, 0.f, NN, Zp, nullptr, SLOTE);
    cheb(b1v, 1);
    ln_pool<<<dim3(64), blk, 0, stream>>>(Sbuf, g1, bt1, hp, zfeat, 0);

    // ---- stage 2: Z_k = h @ W2[k] (packed A, K=64) ----
    gemm_v5<3, false, false, false, 0><<<dim3(8, 64, 6), blk, 0, stream>>>(
        nullptr, nullptr, nullptr, hp, DD, (long)ND, w2p, 0L, (long)DD * DD,
        nullptr, nullptr, nullptr, 1.f, 0.f, DD, Zp, nullptr, SLOTE);
    cheb(b2v, 1);
    ln_pool<<<dim3(64), blk, 0, stream>>>(Sbuf, g2, bt2, hp, zfeat, 128);

    // ---- stage 3: Z_k = h @ W3[k]; Clenshaw -> X0 packed row-major ----
    gemm_v5<3, false, false, false, 0><<<dim3(8, 64, 6), blk, 0, stream>>>(
        nullptr, nullptr, nullptr, hp, DD, (long)ND, w3p, 0L, (long)DD * DD,
        nullptr, nullptr, nullptr, 1.f, 0.f, DD, Zp, nullptr, SLOTE);
    cheb(b3v, 2);

    // ---- AE = relu(X0 X0^T), zero diag ----
    outer_v5<<<dim3(8, 8, 64), blk, 0, stream>>>(X0p, out);

    // ---- heads ----
    heads<<<dim3(64), dim3(64), 0, stream>>>(
        zfeat, p1w, p1b, p2w, p2b, p3w, p3b, s1w, s1b, s2w, s2b, p4w, p4b, outc, outsc);
}

// Round 6
// 873.321 us; speedup vs baseline: 1.4715x; 1.4715x over previous
//
#include <hip/hip_runtime.h>

#define NN 512
#define DD 64
#define BB 64
#define ND (NN * DD)          // 32768

static const long BND = (long)BB * ND;   // 2,097,152

typedef __bf16 bf16x8 __attribute__((ext_vector_type(8)));
typedef float  f32x4  __attribute__((ext_vector_type(4)));

// fp32 -> bf16 round-to-nearest-even
__device__ __forceinline__ unsigned short f2bf(float x) {
    unsigned int u = __float_as_uint(x);
    unsigned int r = u + 0x7fffu + ((u >> 16) & 1u);
    return (unsigned short)(r >> 16);
}
__device__ __forceinline__ float bf2f(unsigned short u) {
    return __uint_as_float(((unsigned int)u) << 16);
}
__device__ __forceinline__ void cvt4(const float4& x, ushort4& h, ushort4& l) {
    float xs[4] = {x.x, x.y, x.z, x.w};
    unsigned short hh[4], ll[4];
#pragma unroll
    for (int i = 0; i < 4; ++i) {
        hh[i] = f2bf(xs[i]);
        ll[i] = f2bf(xs[i] - bf2f(hh[i]));
    }
    h = make_ushort4(hh[0], hh[1], hh[2], hh[3]);
    l = make_ushort4(ll[0], ll[1], ll[2], ll[3]);
}
__device__ __forceinline__ bf16x8 ld_bf8(const unsigned short* p) {
    int4 v = *reinterpret_cast<const int4*>(p);
    return __builtin_bit_cast(bf16x8, v);
}
__device__ __forceinline__ f32x4 mfma16(bf16x8 a, bf16x8 b, f32x4 c) {
    return __builtin_amdgcn_mfma_f32_16x16x32_bf16(a, b, c, 0, 0, 0);
}
// LDS tile [64 r][64 shorts], XOR swizzle (R2-proven: 0 bank conflicts)
__device__ __forceinline__ int swzW4(int r, int c) {   // c = ushort4 group 0..15
    return r * 64 + (((c >> 1) ^ (r & 7)) << 3) + ((c & 1) << 2);
}
__device__ __forceinline__ int swzR(int r, int oct) {  // oct 0..7
    return r * 64 + ((oct ^ (r & 7)) << 3);
}

// ---------------------------------------------------------------------------
// MFMA GEMM v6 = R2's gemm_mfma skeleton (no lambdas) with AMODE for A:
//   AMODE 0: A fp32 row-major -> cvt-split into LDS (byte-exact R2 path)
//   AMODE 2: A pre-split hi/lo bf16 planes row-major -> int4 LDS copy (no cvt)
// B: fp32 [.., f, kdim] -> cvt-split into LDS (R2 path).
// Vm/Zt: fp32 col-major [b][64 f][512 n]; bias[f].
// OUTF 0: fp32 col-major float4 (full-line); OUTF 1: fp32 row-major [n][64].
// 3-term split MFMA (ah*bh + ah*bl + al*bh) ~ fp32 precision.
// ---------------------------------------------------------------------------
template <int AMODE, bool HAS_VM, bool HAS_Z, bool HAS_BIAS, int OUTF>
__global__ __launch_bounds__(256) void gemm_v6(
    const float* __restrict__ Afp,
    const unsigned short* __restrict__ Ah, const unsigned short* __restrict__ Al,
    int lda, long aBatch,
    const float* __restrict__ Bfp, long bBatch, long bZ,
    const float* __restrict__ Vm, const float* __restrict__ Zt,
    const float* __restrict__ bias, float alpha, float beta, int kdim,
    float* __restrict__ outF, long outZ)
{
    const int b = blockIdx.y, z = blockIdx.z;
    const int i0 = blockIdx.x * 64;
    const long aOff = (long)b * aBatch;
    const long bOff = (long)b * bBatch + (long)z * bZ;

    __shared__ __align__(16) unsigned short sAh[4096];
    __shared__ __align__(16) unsigned short sAl[4096];
    __shared__ __align__(16) unsigned short sBh[4096];
    __shared__ __align__(16) unsigned short sBl[4096];

    const int t = threadIdx.x;
    const int w = t >> 6, lane = t & 63;
    const int wr = w >> 1, wc = w & 1;
    const int lr = lane & 15, lg = lane >> 4;

    f32x4 acc[2][2];
#pragma unroll
    for (int m = 0; m < 2; ++m)
#pragma unroll
        for (int n = 0; n < 2; ++n) acc[m][n] = f32x4{0.f, 0.f, 0.f, 0.f};

    const int steps = kdim >> 6;

    // prefetch registers (unused-mode arrays sized 1 and never touched)
    float4 ra[(AMODE == 0) ? 4 : 1];
    int4   pah[(AMODE == 2) ? 2 : 1];
    int4   pal[(AMODE == 2) ? 2 : 1];
    float4 rb[4];

    // ---- prologue prefetch (k0 = 0) ----
    if constexpr (AMODE == 0) {
#pragma unroll
        for (int l = 0; l < 4; ++l) {
            int q = t + l * 256, r = q >> 4, c = q & 15;
            ra[l] = *reinterpret_cast<const float4*>(Afp + aOff + (long)(i0 + r) * lda + c * 4);
        }
    } else {
#pragma unroll
        for (int l = 0; l < 2; ++l) {
            int q = t + l * 256, r = q >> 3, oct = q & 7;
            long g = aOff + (long)(i0 + r) * lda + oct * 8;
            pah[l] = *reinterpret_cast<const int4*>(Ah + g);
            pal[l] = *reinterpret_cast<const int4*>(Al + g);
        }
    }
#pragma unroll
    for (int l = 0; l < 4; ++l) {
        int q = t + l * 256, r = q >> 4, c = q & 15;
        rb[l] = *reinterpret_cast<const float4*>(Bfp + bOff + (long)r * kdim + c * 4);
    }

    for (int s = 0; s < steps; ++s) {
        if (s) __syncthreads();
        // ---- stage to LDS ----
        if constexpr (AMODE == 0) {
#pragma unroll
            for (int l = 0; l < 4; ++l) {
                int q = t + l * 256, r = q >> 4, c = q & 15;
                int idx = swzW4(r, c);
                ushort4 h4, l4;
                cvt4(ra[l], h4, l4);
                *reinterpret_cast<ushort4*>(&sAh[idx]) = h4;
                *reinterpret_cast<ushort4*>(&sAl[idx]) = l4;
            }
        } else {
#pragma unroll
            for (int l = 0; l < 2; ++l) {
                int q = t + l * 256, r = q >> 3, oct = q & 7;
                int idx = r * 64 + ((oct ^ (r & 7)) << 3);
                *reinterpret_cast<int4*>(&sAh[idx]) = pah[l];
                *reinterpret_cast<int4*>(&sAl[idx]) = pal[l];
            }
        }
#pragma unroll
        for (int l = 0; l < 4; ++l) {
            int q = t + l * 256, r = q >> 4, c = q & 15;
            int idx = swzW4(r, c);
            ushort4 h4, l4;
            cvt4(rb[l], h4, l4);
            *reinterpret_cast<ushort4*>(&sBh[idx]) = h4;
            *reinterpret_cast<ushort4*>(&sBl[idx]) = l4;
        }
        __syncthreads();
        // ---- prefetch next K-step while MFMAs run ----
        if (s + 1 < steps) {
            const int k0n = (s + 1) << 6;
            if constexpr (AMODE == 0) {
#pragma unroll
                for (int l = 0; l < 4; ++l) {
                    int q = t + l * 256, r = q >> 4, c = q & 15;
                    ra[l] = *reinterpret_cast<const float4*>(Afp + aOff + (long)(i0 + r) * lda + k0n + c * 4);
                }
            } else {
#pragma unroll
                for (int l = 0; l < 2; ++l) {
                    int q = t + l * 256, r = q >> 3, oct = q & 7;
                    long g = aOff + (long)(i0 + r) * lda + k0n + oct * 8;
                    pah[l] = *reinterpret_cast<const int4*>(Ah + g);
                    pal[l] = *reinterpret_cast<const int4*>(Al + g);
                }
            }
#pragma unroll
            for (int l = 0; l < 4; ++l) {
                int q = t + l * 256, r = q >> 4, c = q & 15;
                rb[l] = *reinterpret_cast<const float4*>(Bfp + bOff + (long)r * kdim + k0n + c * 4);
            }
        }
        // ---- MFMA (R2-exact) ----
#pragma unroll
        for (int c2 = 0; c2 < 2; ++c2) {
            const int oct = c2 * 4 + lg;
            bf16x8 a_h[2], a_l[2], b_h[2], b_l[2];
#pragma unroll
            for (int m = 0; m < 2; ++m) {
                int row = wr * 32 + m * 16 + lr;
                int ai = swzR(row, oct);
                a_h[m] = ld_bf8(&sAh[ai]);
                a_l[m] = ld_bf8(&sAl[ai]);
                int col = wc * 32 + m * 16 + lr;
                int bi = swzR(col, oct);
                b_h[m] = ld_bf8(&sBh[bi]);
                b_l[m] = ld_bf8(&sBl[bi]);
            }
#pragma unroll
            for (int m = 0; m < 2; ++m)
#pragma unroll
                for (int n = 0; n < 2; ++n) {
                    acc[m][n] = mfma16(a_h[m], b_h[n], acc[m][n]);
                    acc[m][n] = mfma16(a_h[m], b_l[n], acc[m][n]);
                    acc[m][n] = mfma16(a_l[m], b_h[n], acc[m][n]);
                }
        }
    }

    // ---- epilogue (R2-exact): C/D frag col = lane&15, row = (lane>>4)*4 + reg ----
    const long cOff = (long)b * ND;
    const long oOff = (long)z * outZ + cOff;
#pragma unroll
    for (int m = 0; m < 2; ++m) {
        const int nb = i0 + wr * 32 + m * 16 + lg * 4;
#pragma unroll
        for (int n = 0; n < 2; ++n) {
            const int f = wc * 32 + n * 16 + lr;
            float4 v;
            v.x = alpha * acc[m][n][0]; v.y = alpha * acc[m][n][1];
            v.z = alpha * acc[m][n][2]; v.w = alpha * acc[m][n][3];
            if (HAS_VM) {
                float4 mv = *reinterpret_cast<const float4*>(Vm + cOff + (long)f * NN + nb);
                v.x += beta * mv.x; v.y += beta * mv.y; v.z += beta * mv.z; v.w += beta * mv.w;
            }
            if (HAS_Z) {
                float4 zz = *reinterpret_cast<const float4*>(Zt + cOff + (long)f * NN + nb);
                v.x += zz.x; v.y += zz.y; v.z += zz.z; v.w += zz.w;
            }
            if (HAS_BIAS) {
                float bf = bias[f];
                v.x += bf; v.y += bf; v.z += bf; v.w += bf;
            }
            if (OUTF == 0) {
                *reinterpret_cast<float4*>(outF + oOff + (long)f * NN + nb) = v;
            } else {
                float* __restrict__ outb = outF + cOff;
                outb[(long)(nb + 0) * DD + f] = v.x;
                outb[(long)(nb + 1) * DD + f] = v.y;
                outb[(long)(nb + 2) * DD + f] = v.z;
                outb[(long)(nb + 3) * DD + f] = v.w;
            }
        }
    }
}

// ---------------------------------------------------------------------------
// fp32 -> hi/lo short planes (layout preserved) — for gso / X
// ---------------------------------------------------------------------------
__global__ __launch_bounds__(256) void split_planes(
    const float* __restrict__ in, unsigned short* __restrict__ oh,
    unsigned short* __restrict__ ol, long n4)
{
    long i = (long)blockIdx.x * 256 + threadIdx.x;
    const long stride = (long)gridDim.x * 256;
    for (; i < n4; i += stride) {
        float4 v = reinterpret_cast<const float4*>(in)[i];
        ushort4 h4, l4;
        cvt4(v, h4, l4);
        reinterpret_cast<ushort4*>(oh)[i] = h4;
        reinterpret_cast<ushort4*>(ol)[i] = l4;
    }
}

// ---------------------------------------------------------------------------
// AE[b,i,j] = relu(dot(X0[b,i,:], X0[b,j,:])), diag zeroed (R2-exact).
// X0 fp32 row-major [512][64].
// ---------------------------------------------------------------------------
__global__ __launch_bounds__(256) void outer_v6(
    const float* __restrict__ X0, float* __restrict__ AE)
{
    const int b = blockIdx.z;
    const int j0 = blockIdx.x * 64, i0 = blockIdx.y * 64;
    const float* __restrict__ Xb = X0 + (long)b * ND;

    __shared__ __align__(16) unsigned short sIh[4096];
    __shared__ __align__(16) unsigned short sIl[4096];
    __shared__ __align__(16) unsigned short sJh[4096];
    __shared__ __align__(16) unsigned short sJl[4096];

    const int t = threadIdx.x;
    const int w = t >> 6, lane = t & 63;
    const int wr = w >> 1, wc = w & 1;
    const int lr = lane & 15, lg = lane >> 4;

#pragma unroll
    for (int l = 0; l < 4; ++l) {
        int q = t + l * 256;
        int r = q >> 4, c = q & 15;
        int idx = swzW4(r, c);
        ushort4 h4, l4;
        float4 vi = *reinterpret_cast<const float4*>(Xb + (long)(i0 + r) * DD + c * 4);
        cvt4(vi, h4, l4);
        *reinterpret_cast<ushort4*>(&sIh[idx]) = h4;
        *reinterpret_cast<ushort4*>(&sIl[idx]) = l4;
        float4 vj = *reinterpret_cast<const float4*>(Xb + (long)(j0 + r) * DD + c * 4);
        cvt4(vj, h4, l4);
        *reinterpret_cast<ushort4*>(&sJh[idx]) = h4;
        *reinterpret_cast<ushort4*>(&sJl[idx]) = l4;
    }
    __syncthreads();

    f32x4 acc[2][2];
#pragma unroll
    for (int m = 0; m < 2; ++m)
#pragma unroll
        for (int n = 0; n < 2; ++n) acc[m][n] = f32x4{0.f, 0.f, 0.f, 0.f};

#pragma unroll
    for (int c2 = 0; c2 < 2; ++c2) {
        const int oct = c2 * 4 + lg;
        bf16x8 a_h[2], a_l[2], b_h[2], b_l[2];
#pragma unroll
        for (int m = 0; m < 2; ++m) {
            int row = wr * 32 + m * 16 + lr;
            a_h[m] = ld_bf8(&sIh[swzR(row, oct)]);
            a_l[m] = ld_bf8(&sIl[swzR(row, oct)]);
            int col = wc * 32 + m * 16 + lr;
            b_h[m] = ld_bf8(&sJh[swzR(col, oct)]);
            b_l[m] = ld_bf8(&sJl[swzR(col, oct)]);
        }
#pragma unroll
        for (int m = 0; m < 2; ++m)
#pragma unroll
            for (int n = 0; n < 2; ++n) {
                acc[m][n] = mfma16(a_h[m], b_h[n], acc[m][n]);
                acc[m][n] = mfma16(a_h[m], b_l[n], acc[m][n]);
                acc[m][n] = mfma16(a_l[m], b_h[n], acc[m][n]);
            }
    }

    float* __restrict__ AEb = AE + (long)b * NN * NN;
#pragma unroll
    for (int m = 0; m < 2; ++m) {
        const int ib = i0 + wr * 32 + m * 16 + lg * 4;
#pragma unroll
        for (int n = 0; n < 2; ++n) {
            const int jc = j0 + wc * 32 + n * 16 + lr;
#pragma unroll
            for (int jj = 0; jj < 4; ++jj) {
                float v = fmaxf(acc[m][n][jj], 0.f);
                if (ib + jj == jc) v = 0.f;
                AEb[(long)(ib + jj) * NN + jc] = v;
            }
        }
    }
}

// ---------------------------------------------------------------------------
// LayerNorm over [N,D] + relu + mean/max pool. pre: fp32 col-major [64][512].
// h out: hi/lo bf16 planes row-major [512][64] (128B-contiguous per 16-lane group).
// ---------------------------------------------------------------------------
__global__ __launch_bounds__(256) void ln_pool(
    const float* __restrict__ pre, const float* __restrict__ gamma,
    const float* __restrict__ beta,
    unsigned short* __restrict__ hh, unsigned short* __restrict__ hl,
    float* __restrict__ zfeat, int zoff)
{
    const int b = blockIdx.x;
    const float* __restrict__ p = pre + (long)b * ND;
    const int t = threadIdx.x;

    float s = 0.f, s2 = 0.f;
    for (int i = t * 4; i < ND; i += 1024) {
        float4 v = *reinterpret_cast<const float4*>(p + i);
        s  += v.x + v.y + v.z + v.w;
        s2 += v.x * v.x + v.y * v.y + v.z * v.z + v.w * v.w;
    }
#pragma unroll
    for (int off = 32; off > 0; off >>= 1) {
        s  += __shfl_down(s, off, 64);
        s2 += __shfl_down(s2, off, 64);
    }
    __shared__ float red[8];
    if ((t & 63) == 0) { red[(t >> 6) * 2] = s; red[(t >> 6) * 2 + 1] = s2; }
    __syncthreads();
    __shared__ float mu_s, rstd_s;
    if (t == 0) {
        float ts  = red[0] + red[2] + red[4] + red[6];
        float ts2 = red[1] + red[3] + red[5] + red[7];
        float mu  = ts * (1.f / ND);
        float var = ts2 * (1.f / ND) - mu * mu;
        mu_s = mu; rstd_s = rsqrtf(var + 1e-5f);
    }
    __syncthreads();
    const float mu = mu_s, rstd = rstd_s;

    const int f4 = (t & 15) * 4, nt = t >> 4;
    float sum4[4] = {0.f, 0.f, 0.f, 0.f};
    float max4[4] = {0.f, 0.f, 0.f, 0.f};
    for (int n = nt; n < NN; n += 16) {
        float4 g4 = *reinterpret_cast<const float4*>(gamma + (long)n * DD + f4);
        float4 be = *reinterpret_cast<const float4*>(beta  + (long)n * DD + f4);
        float4 v;
        v.x = fmaxf((p[(long)(f4 + 0) * NN + n] - mu) * rstd * g4.x + be.x, 0.f);
        v.y = fmaxf((p[(long)(f4 + 1) * NN + n] - mu) * rstd * g4.y + be.y, 0.f);
        v.z = fmaxf((p[(long)(f4 + 2) * NN + n] - mu) * rstd * g4.z + be.z, 0.f);
        v.w = fmaxf((p[(long)(f4 + 3) * NN + n] - mu) * rstd * g4.w + be.w, 0.f);
        ushort4 h4, l4;
        cvt4(v, h4, l4);
        *reinterpret_cast<ushort4*>(hh + (long)b * ND + (long)n * DD + f4) = h4;
        *reinterpret_cast<ushort4*>(hl + (long)b * ND + (long)n * DD + f4) = l4;
        sum4[0] += v.x; sum4[1] += v.y; sum4[2] += v.z; sum4[3] += v.w;
        max4[0] = fmaxf(max4[0], v.x); max4[1] = fmaxf(max4[1], v.y);
        max4[2] = fmaxf(max4[2], v.z); max4[3] = fmaxf(max4[3], v.w);
    }
    __shared__ float rs[16][64], rm[16][64];
#pragma unroll
    for (int j = 0; j < 4; ++j) { rs[nt][f4 + j] = sum4[j]; rm[nt][f4 + j] = max4[j]; }
    __syncthreads();
    if (t < 64) {
        float ss = 0.f, mm = 0.f;
#pragma unroll
        for (int k = 0; k < 16; ++k) { ss += rs[k][t]; mm = fmaxf(mm, rm[k][t]); }
        zfeat[b * 256 + zoff + t]      = ss * (1.f / NN);
        zfeat[b * 256 + zoff + 64 + t] = mm;
    }
}

// ---------------------------------------------------------------------------
// W[z][kdim][64] fp32 -> fp32 transposed [z][64][kdim] (R2-exact)
// ---------------------------------------------------------------------------
__global__ void transW(const float* __restrict__ W, float* __restrict__ Wt,
                       int kdim, int total)
{
    int o = blockIdx.x * 256 + threadIdx.x;
    if (o >= total) return;
    int per = 64 * kdim;
    int zz = o / per, r = o % per;
    int f = r / kdim, k = r % kdim;
    Wt[o] = W[((long)zz * kdim + k) * 64 + f];
}

// ---------------------------------------------------------------------------
// Tiny MLP heads (unchanged).
// ---------------------------------------------------------------------------
__global__ __launch_bounds__(64) void heads(
    const float* __restrict__ zfeat,
    const float* __restrict__ p1w, const float* __restrict__ p1b,
    const float* __restrict__ p2w, const float* __restrict__ p2b,
    const float* __restrict__ p3w, const float* __restrict__ p3b,
    const float* __restrict__ s1w, const float* __restrict__ s1b,
    const float* __restrict__ s2w, const float* __restrict__ s2b,
    const float* __restrict__ p4w, const float* __restrict__ p4b,
    float* __restrict__ outc, float* __restrict__ outs)
{
    const int b = blockIdx.x, t = threadIdx.x;
    __shared__ float zf[256], v1[64], v2[64], lg[2];
    for (int i = t; i < 256; i += 64) zf[i] = zfeat[b * 256 + i];
    __syncthreads();

    float a = p1b[t];
    for (int z = 0; z < 256; ++z) a = fmaf(zf[z], p1w[z * 64 + t], a);
    v1[t] = a >= 0.f ? a : 0.2f * a;
    __syncthreads();
    float a2 = p2b[t];
    for (int z = 0; z < 64; ++z) a2 = fmaf(v1[z], p2w[z * 64 + t], a2);
    v2[t] = a2 >= 0.f ? a2 : 0.2f * a2;
    __syncthreads();
    if (t < 4) {
        float a3 = p3b[t];
        for (int z = 0; z < 64; ++z) a3 = fmaf(v2[z], p3w[z * 4 + t], a3);
        outc[b * 4 + t] = 1.f / (1.f + expf(-a3));
    }
    __syncthreads();

    float c = s1b[t];
    for (int z = 0; z < 256; ++z) c = fmaf(zf[z], s1w[z * 64 + t], c);
    v1[t] = c >= 0.f ? c : 0.2f * c;
    __syncthreads();
    float c2 = s2b[t];
    for (int z = 0; z < 64; ++z) c2 = fmaf(v1[z], s2w[z * 64 + t], c2);
    v2[t] = c2 >= 0.f ? c2 : 0.2f * c2;
    __syncthreads();
    if (t < 2) {
        float d = p4b[t];
        for (int z = 0; z < 64; ++z) d = fmaf(v2[z], p4w[z * 2 + t], d);
        lg[t] = d;
    }
    __syncthreads();
    if (t < 2) {
        float m = fmaxf(lg[0], lg[1]);
        float lse = m + logf(expf(lg[0] - m) + expf(lg[1] - m));
        outs[b * 2 + t] = lg[t] - lse;
    }
}

// ---------------------------------------------------------------------------
// In-place Clenshaw over fp32 slots s0..s5 (col-major [b][64f][512n] in d_out):
//   g1: s4 <- 2A*s5 + s4      g2: s5 <- 2A*s4 - s5 + s3
//   g3: s4 <- 2A*s5 - s4 + s2 g4: s5 <- 2A*s4 - s5 + s1
//   g5: out <- A*s5 - s4 + s0 + bias
// Epilogue Vm/Zt reads are same-thread-same-coords (R3-proven safe).
// ---------------------------------------------------------------------------
template <int AM>
static void chebRun(const float* Afp, const unsigned short* Ahp, const unsigned short* Alp,
                    float* slots, const float* bias, int outf, float* Sout, float* X0f,
                    hipStream_t stream)
{
    const dim3 blk(256), grd(8, 64, 1);
    const long AB = (long)NN * NN;
    float* s0 = slots + 0 * BND;
    float* s1 = slots + 1 * BND;
    float* s2 = slots + 2 * BND;
    float* s3 = slots + 3 * BND;
    float* s4 = slots + 4 * BND;
    float* s5 = slots + 5 * BND;
    gemm_v6<AM, false, true, false, 0><<<grd, blk, 0, stream>>>(
        Afp, Ahp, Alp, NN, AB, s5, (long)ND, 0L, nullptr, s4, nullptr,
        2.f, 0.f, NN, s4, 0L);
    gemm_v6<AM, true, true, false, 0><<<grd, blk, 0, stream>>>(
        Afp, Ahp, Alp, NN, AB, s4, (long)ND, 0L, s5, s3, nullptr,
        2.f, -1.f, NN, s5, 0L);
    gemm_v6<AM, true, true, false, 0><<<grd, blk, 0, stream>>>(
        Afp, Ahp, Alp, NN, AB, s5, (long)ND, 0L, s4, s2, nullptr,
        2.f, -1.f, NN, s4, 0L);
    gemm_v6<AM, true, true, false, 0><<<grd, blk, 0, stream>>>(
        Afp, Ahp, Alp, NN, AB, s4, (long)ND, 0L, s5, s1, nullptr,
        2.f, -1.f, NN, s5, 0L);
    if (outf == 0)
        gemm_v6<AM, true, true, true, 0><<<grd, blk, 0, stream>>>(
            Afp, Ahp, Alp, NN, AB, s5, (long)ND, 0L, s4, s0, bias,
            1.f, -1.f, NN, Sout, 0L);
    else
        gemm_v6<AM, true, true, true, 1><<<grd, blk, 0, stream>>>(
            Afp, Ahp, Alp, NN, AB, s5, (long)ND, 0L, s4, s0, bias,
            1.f, -1.f, NN, X0f, 0L);
}

extern "C" void kernel_launch(void* const* d_in, const int* in_sizes, int n_in,
                              void* d_out, int out_size, void* d_ws, size_t ws_size,
                              hipStream_t stream)
{
    const float* A   = (const float*)d_in[0];
    const float* X   = (const float*)d_in[1];
    const float* W1  = (const float*)d_in[2];
    const float* b1v = (const float*)d_in[3];
    const float* W2  = (const float*)d_in[4];
    const float* b2v = (const float*)d_in[5];
    const float* W3  = (const float*)d_in[6];
    const float* b3v = (const float*)d_in[7];
    const float* g1  = (const float*)d_in[8];
    const float* bt1 = (const float*)d_in[9];
    const float* g2  = (const float*)d_in[10];
    const float* bt2 = (const float*)d_in[11];
    const float* p1w = (const float*)d_in[12];
    const float* p1b = (const float*)d_in[13];
    const float* p2w = (const float*)d_in[14];
    const float* p2b = (const float*)d_in[15];
    const float* p3w = (const float*)d_in[16];
    const float* p3b = (const float*)d_in[17];
    const float* s1w = (const float*)d_in[18];
    const float* s1b = (const float*)d_in[19];
    const float* s2w = (const float*)d_in[20];
    const float* s2b = (const float*)d_in[21];
    const float* p4w = (const float*)d_in[22];
    const float* p4b = (const float*)d_in[23];

    float* out   = (float*)d_out;
    float* slots = out;                      // 6 fp32 slots, 50.3 MB
    float* Sbuf  = out + 6 * BND;            // 8.4 MB pre-LN buffer (total 58.7 < 67.1)
    float* outc  = out + (long)BB * NN * NN;
    float* outsc = outc + BB * 4;

    // ws layout: W1t | W2t | W3t | zfeat | hh,hl (X0f aliases) | Ahp,Alp | Xhp,Xlp
    float* wsf = (float*)d_ws;
    float* W1t = wsf;                                   // 196,608 floats
    float* W2t = wsf + 196608;                          // 24,576
    float* W3t = W2t + 24576;                           // 24,576
    float* zfeat = W3t + 24576;                         // 16,384
    unsigned short* hh = (unsigned short*)(zfeat + 16384);   // byte 1,048,576
    unsigned short* hl = hh + 2097152;
    float* X0f = (float*)hh;                            // aliases hh+hl (8.4 MB)
    unsigned short* Ahp = (unsigned short*)((char*)d_ws + 9437184);
    unsigned short* Alp = Ahp + 16777216;               // ends at byte 76,546,048
    unsigned short* Xhp = Alp + 16777216;
    unsigned short* Xlp = Xhp + 16777216;               // ends at byte 143,654,912

    const bool splitA = ws_size >= 76546048ULL;   // proven-available threshold (R4/R5)
    const bool splitX = ws_size >= 143654912ULL;

    const dim3 blk(256);
    const long AB = (long)NN * NN;

    transW<<<dim3((6 * NN * DD + 255) / 256), blk, 0, stream>>>(W1, W1t, NN, 6 * NN * DD);
    transW<<<dim3((6 * DD * DD + 255) / 256), blk, 0, stream>>>(W2, W2t, DD, 6 * DD * DD);
    transW<<<dim3((6 * DD * DD + 255) / 256), blk, 0, stream>>>(W3, W3t, DD, 6 * DD * DD);
    if (splitA)
        split_planes<<<dim3(2048), blk, 0, stream>>>(A, Ahp, Alp, (long)BB * NN * NN / 4);
    if (splitX)
        split_planes<<<dim3(2048), blk, 0, stream>>>(X, Xhp, Xlp, (long)BB * NN * NN / 4);

    auto cheb = [&](const float* bias, int outf) {
        if (splitA) chebRun<2>(nullptr, Ahp, Alp, slots, bias, outf, Sbuf, X0f, stream);
        else        chebRun<0>(A, nullptr, nullptr, slots, bias, outf, Sbuf, X0f, stream);
    };

    // ---- stage 1: Z_k = X @ W1[k] -> slots ----
    if (splitX)
        gemm_v6<2, false, false, false, 0><<<dim3(8, 64, 6), blk, 0, stream>>>(
            nullptr, Xhp, Xlp, NN, AB, W1t, 0L, (long)NN * DD,
            nullptr, nullptr, nullptr, 1.f, 0.f, NN, slots, BND);
    else
        gemm_v6<0, false, false, false, 0><<<dim3(8, 64, 6), blk, 0, stream>>>(
            X, nullptr, nullptr, NN, AB, W1t, 0L, (long)NN * DD,
            nullptr, nullptr, nullptr, 1.f, 0.f, NN, slots, BND);
    cheb(b1v, 0);
    ln_pool<<<dim3(64), blk, 0, stream>>>(Sbuf, g1, bt1, hh, hl, zfeat, 0);

    // ---- stage 2: Z_k = h @ W2[k] (h planes, K=64) ----
    gemm_v6<2, false, false, false, 0><<<dim3(8, 64, 6), blk, 0, stream>>>(
        nullptr, hh, hl, DD, (long)ND, W2t, 0L, (long)DD * DD,
        nullptr, nullptr, nullptr, 1.f, 0.f, DD, slots, BND);
    cheb(b2v, 0);
    ln_pool<<<dim3(64), blk, 0, stream>>>(Sbuf, g2, bt2, hh, hl, zfeat, 128);

    // ---- stage 3: Z_k = h @ W3[k]; Clenshaw -> X0 fp32 row-major (aliases h) ----
    gemm_v6<2, false, false, false, 0><<<dim3(8, 64, 6), blk, 0, stream>>>(
        nullptr, hh, hl, DD, (long)ND, W3t, 0L, (long)DD * DD,
        nullptr, nullptr, nullptr, 1.f, 0.f, DD, slots, BND);
    cheb(b3v, 1);

    // ---- AE = relu(X0 X0^T), zero diag ----
    outer_v6<<<dim3(8, 8, 64), blk, 0, stream>>>(X0f, out);

    // ---- heads ----
    heads<<<dim3(64), dim3(64), 0, stream>>>(
        zfeat, p1w, p1b, p2w, p2b, p3w, p3b, s1w, s1b, s2w, s2b, p4w, p4b, outc, outsc);
}

// Round 7
// 624.847 us; speedup vs baseline: 2.0567x; 1.3977x over previous
//
#include <hip/hip_runtime.h>

#define NN 512
#define DD 64
#define BB 64
#define ND (NN * DD)          // 32768

static const long BND = (long)BB * ND;   // 2,097,152

typedef __bf16 bf16x8 __attribute__((ext_vector_type(8)));
typedef float  f32x4  __attribute__((ext_vector_type(4)));

// fp32 -> bf16 round-to-nearest-even
__device__ __forceinline__ unsigned short f2bf(float x) {
    unsigned int u = __float_as_uint(x);
    unsigned int r = u + 0x7fffu + ((u >> 16) & 1u);
    return (unsigned short)(r >> 16);
}
__device__ __forceinline__ float bf2f(unsigned short u) {
    return __uint_as_float(((unsigned int)u) << 16);
}
__device__ __forceinline__ void cvt4(const float4& x, ushort4& h, ushort4& l) {
    float xs[4] = {x.x, x.y, x.z, x.w};
    unsigned short hh[4], ll[4];
#pragma unroll
    for (int i = 0; i < 4; ++i) {
        hh[i] = f2bf(xs[i]);
        ll[i] = f2bf(xs[i] - bf2f(hh[i]));
    }
    h = make_ushort4(hh[0], hh[1], hh[2], hh[3]);
    l = make_ushort4(ll[0], ll[1], ll[2], ll[3]);
}
__device__ __forceinline__ bf16x8 ld_bf8(const unsigned short* p) {
    int4 v = *reinterpret_cast<const int4*>(p);
    return __builtin_bit_cast(bf16x8, v);
}
__device__ __forceinline__ f32x4 mfma16(bf16x8 a, bf16x8 b, f32x4 c) {
    return __builtin_amdgcn_mfma_f32_16x16x32_bf16(a, b, c, 0, 0, 0);
}
// LDS tile [64 r][64 shorts], XOR swizzle (R2-proven: 0 bank conflicts)
__device__ __forceinline__ int swzW4(int r, int c) {   // c = ushort4 group 0..15
    return r * 64 + (((c >> 1) ^ (r & 7)) << 3) + ((c & 1) << 2);
}
__device__ __forceinline__ int swzR(int r, int oct) {  // oct 0..7
    return r * 64 + ((oct ^ (r & 7)) << 3);
}
// async global->LDS, 16 B per lane; LDS base must be wave-uniform (HW adds lane*16)
__device__ __forceinline__ void gload16(const unsigned short* g, unsigned short* l) {
    __builtin_amdgcn_global_load_lds(
        (const __attribute__((address_space(1))) unsigned int*)g,
        (__attribute__((address_space(3))) unsigned int*)l, 16, 0, 0);
}

// ---------------------------------------------------------------------------
// MFMA GEMM v7 = R2 skeleton; A staged by AMODE:
//   AMODE 0: A fp32 row-major -> cvt-split into LDS (byte-exact R2 path)
//   AMODE 2: A hi/lo planes row-major -> global_load_lds direct (0 VGPR, 0 cvt),
//            LDS double-buffered; source octet pre-swizzled j^(r&7) so the
//            R2 read addressing (swzR) is preserved (rule #21 involution).
// B: fp32 [.., f, kdim] -> cvt-split into LDS (R2-exact, rb[4] prefetch).
// Vm/Zt: fp32 col-major [b][64 f][512 n]; bias[f].
// OUTF 0: fp32 col-major float4 (full-line); OUTF 1: fp32 row-major [n][64].
// 3-term split MFMA (ah*bh + ah*bl + al*bh) ~ fp32 precision.
// ---------------------------------------------------------------------------
template <int AMODE, bool HAS_VM, bool HAS_Z, bool HAS_BIAS, int OUTF>
__global__ __launch_bounds__(256) void gemm_v7(
    const float* __restrict__ Afp,
    const unsigned short* __restrict__ Ah, const unsigned short* __restrict__ Al,
    int lda, long aBatch,
    const float* __restrict__ Bfp, long bBatch, long bZ,
    const float* __restrict__ Vm, const float* __restrict__ Zt,
    const float* __restrict__ bias, float alpha, float beta, int kdim,
    float* __restrict__ outF, long outZ)
{
    const int b = blockIdx.y, z = blockIdx.z;
    const int i0 = blockIdx.x * 64;
    const long aOff = (long)b * aBatch;
    const long bOff = (long)b * bBatch + (long)z * bZ;

    __shared__ __align__(16) unsigned short sAh[8192];   // 2 bufs x 4096 (AMODE 2)
    __shared__ __align__(16) unsigned short sAl[8192];
    __shared__ __align__(16) unsigned short sBh[4096];
    __shared__ __align__(16) unsigned short sBl[4096];

    const int t = threadIdx.x;
    const int w = t >> 6, lane = t & 63;
    const int wr = w >> 1, wc = w & 1;
    const int lr = lane & 15, lg = lane >> 4;

    f32x4 acc[2][2];
#pragma unroll
    for (int m = 0; m < 2; ++m)
#pragma unroll
        for (int n = 0; n < 2; ++n) acc[m][n] = f32x4{0.f, 0.f, 0.f, 0.f};

    const int steps = kdim >> 6;

    float4 ra[(AMODE == 0) ? 4 : 1];   // fp32 A prefetch (AMODE 0 only)
    float4 rb[4];                      // B prefetch (R2-exact)

    // ---- A issue for step k0 into LDS buffer `buf` (AMODE 2) ----
    // linear octet o = c*256 + w*64 + lane; row r = o>>3, j = o&7;
    // LDS[o] <- global octet (r, j^(r&7)); read side = swzR (identical to R2).
    auto issueA = [&](int buf, int k0) {
#pragma unroll
        for (int c = 0; c < 2; ++c) {
            const int o = c * 256 + w * 64 + lane;
            const int r = o >> 3, j = o & 7;
            const long src = aOff + (long)(i0 + r) * lda + k0 + ((j ^ (r & 7)) << 3);
            const int dst = buf * 4096 + (c * 256 + w * 64) * 8;  // wave-uniform
            gload16(Ah + src, &sAh[dst]);
            gload16(Al + src, &sAl[dst]);
        }
    };

    // ---- prologue ----
    if constexpr (AMODE == 0) {
#pragma unroll
        for (int l = 0; l < 4; ++l) {
            int q = t + l * 256, r = q >> 4, c = q & 15;
            ra[l] = *reinterpret_cast<const float4*>(Afp + aOff + (long)(i0 + r) * lda + c * 4);
        }
    } else {
        issueA(0, 0);
    }
#pragma unroll
    for (int l = 0; l < 4; ++l) {
        int q = t + l * 256, r = q >> 4, c = q & 15;
        rb[l] = *reinterpret_cast<const float4*>(Bfp + bOff + (long)r * kdim + c * 4);
    }

    for (int s = 0; s < steps; ++s) {
        if (s) __syncthreads();           // barrier T: prev MFMA readers done
        if constexpr (AMODE == 0) {
#pragma unroll
            for (int l = 0; l < 4; ++l) {
                int q = t + l * 256, r = q >> 4, c = q & 15;
                int idx = swzW4(r, c);
                ushort4 h4, l4;
                cvt4(ra[l], h4, l4);
                *reinterpret_cast<ushort4*>(&sAh[idx]) = h4;
                *reinterpret_cast<ushort4*>(&sAl[idx]) = l4;
            }
        }
#pragma unroll
        for (int l = 0; l < 4; ++l) {
            int q = t + l * 256, r = q >> 4, c = q & 15;
            int idx = swzW4(r, c);
            ushort4 h4, l4;
            cvt4(rb[l], h4, l4);
            *reinterpret_cast<ushort4*>(&sBh[idx]) = h4;
            *reinterpret_cast<ushort4*>(&sBl[idx]) = l4;
        }
        __syncthreads();                  // barrier M: drains A vmcnt + B ds_writes
        const int abuf = (AMODE == 2) ? (s & 1) : 0;
        // ---- prefetch next step while MFMAs run ----
        if (s + 1 < steps) {
            const int k0n = (s + 1) << 6;
            if constexpr (AMODE == 0) {
#pragma unroll
                for (int l = 0; l < 4; ++l) {
                    int q = t + l * 256, r = q >> 4, c = q & 15;
                    ra[l] = *reinterpret_cast<const float4*>(Afp + aOff + (long)(i0 + r) * lda + k0n + c * 4);
                }
            } else {
                issueA((s + 1) & 1, k0n);     // in flight during this step's MFMAs
            }
#pragma unroll
            for (int l = 0; l < 4; ++l) {
                int q = t + l * 256, r = q >> 4, c = q & 15;
                rb[l] = *reinterpret_cast<const float4*>(Bfp + bOff + (long)r * kdim + k0n + c * 4);
            }
        }
        // ---- MFMA (R2-exact) ----
#pragma unroll
        for (int c2 = 0; c2 < 2; ++c2) {
            const int oct = c2 * 4 + lg;
            bf16x8 a_h[2], a_l[2], b_h[2], b_l[2];
#pragma unroll
            for (int m = 0; m < 2; ++m) {
                int row = wr * 32 + m * 16 + lr;
                int ai = abuf * 4096 + swzR(row, oct);
                a_h[m] = ld_bf8(&sAh[ai]);
                a_l[m] = ld_bf8(&sAl[ai]);
                int col = wc * 32 + m * 16 + lr;
                int bi = swzR(col, oct);
                b_h[m] = ld_bf8(&sBh[bi]);
                b_l[m] = ld_bf8(&sBl[bi]);
            }
#pragma unroll
            for (int m = 0; m < 2; ++m)
#pragma unroll
                for (int n = 0; n < 2; ++n) {
                    acc[m][n] = mfma16(a_h[m], b_h[n], acc[m][n]);
                    acc[m][n] = mfma16(a_h[m], b_l[n], acc[m][n]);
                    acc[m][n] = mfma16(a_l[m], b_h[n], acc[m][n]);
                }
        }
    }

    // ---- epilogue (R2-exact): C/D frag col = lane&15, row = (lane>>4)*4 + reg ----
    const long cOff = (long)b * ND;
    const long oOff = (long)z * outZ + cOff;
#pragma unroll
    for (int m = 0; m < 2; ++m) {
        const int nb = i0 + wr * 32 + m * 16 + lg * 4;
#pragma unroll
        for (int n = 0; n < 2; ++n) {
            const int f = wc * 32 + n * 16 + lr;
            float4 v;
            v.x = alpha * acc[m][n][0]; v.y = alpha * acc[m][n][1];
            v.z = alpha * acc[m][n][2]; v.w = alpha * acc[m][n][3];
            if (HAS_VM) {
                float4 mv = *reinterpret_cast<const float4*>(Vm + cOff + (long)f * NN + nb);
                v.x += beta * mv.x; v.y += beta * mv.y; v.z += beta * mv.z; v.w += beta * mv.w;
            }
            if (HAS_Z) {
                float4 zz = *reinterpret_cast<const float4*>(Zt + cOff + (long)f * NN + nb);
                v.x += zz.x; v.y += zz.y; v.z += zz.z; v.w += zz.w;
            }
            if (HAS_BIAS) {
                float bf = bias[f];
                v.x += bf; v.y += bf; v.z += bf; v.w += bf;
            }
            if (OUTF == 0) {
                *reinterpret_cast<float4*>(outF + oOff + (long)f * NN + nb) = v;
            } else {
                float* __restrict__ outb = outF + cOff;
                outb[(long)(nb + 0) * DD + f] = v.x;
                outb[(long)(nb + 1) * DD + f] = v.y;
                outb[(long)(nb + 2) * DD + f] = v.z;
                outb[(long)(nb + 3) * DD + f] = v.w;
            }
        }
    }
}

// ---------------------------------------------------------------------------
// fp32 -> hi/lo short planes (layout preserved) — for gso / X
// ---------------------------------------------------------------------------
__global__ __launch_bounds__(256) void split_planes(
    const float* __restrict__ in, unsigned short* __restrict__ oh,
    unsigned short* __restrict__ ol, long n4)
{
    long i = (long)blockIdx.x * 256 + threadIdx.x;
    const long stride = (long)gridDim.x * 256;
    for (; i < n4; i += stride) {
        float4 v = reinterpret_cast<const float4*>(in)[i];
        ushort4 h4, l4;
        cvt4(v, h4, l4);
        reinterpret_cast<ushort4*>(oh)[i] = h4;
        reinterpret_cast<ushort4*>(ol)[i] = l4;
    }
}

// ---------------------------------------------------------------------------
// AE[b,i,j] = relu(dot(X0[b,i,:], X0[b,j,:])), diag zeroed (R2-exact).
// X0 fp32 row-major [512][64].
// ---------------------------------------------------------------------------
__global__ __launch_bounds__(256) void outer_v7(
    const float* __restrict__ X0, float* __restrict__ AE)
{
    const int b = blockIdx.z;
    const int j0 = blockIdx.x * 64, i0 = blockIdx.y * 64;
    const float* __restrict__ Xb = X0 + (long)b * ND;

    __shared__ __align__(16) unsigned short sIh[4096];
    __shared__ __align__(16) unsigned short sIl[4096];
    __shared__ __align__(16) unsigned short sJh[4096];
    __shared__ __align__(16) unsigned short sJl[4096];

    const int t = threadIdx.x;
    const int w = t >> 6, lane = t & 63;
    const int wr = w >> 1, wc = w & 1;
    const int lr = lane & 15, lg = lane >> 4;

#pragma unroll
    for (int l = 0; l < 4; ++l) {
        int q = t + l * 256;
        int r = q >> 4, c = q & 15;
        int idx = swzW4(r, c);
        ushort4 h4, l4;
        float4 vi = *reinterpret_cast<const float4*>(Xb + (long)(i0 + r) * DD + c * 4);
        cvt4(vi, h4, l4);
        *reinterpret_cast<ushort4*>(&sIh[idx]) = h4;
        *reinterpret_cast<ushort4*>(&sIl[idx]) = l4;
        float4 vj = *reinterpret_cast<const float4*>(Xb + (long)(j0 + r) * DD + c * 4);
        cvt4(vj, h4, l4);
        *reinterpret_cast<ushort4*>(&sJh[idx]) = h4;
        *reinterpret_cast<ushort4*>(&sJl[idx]) = l4;
    }
    __syncthreads();

    f32x4 acc[2][2];
#pragma unroll
    for (int m = 0; m < 2; ++m)
#pragma unroll
        for (int n = 0; n < 2; ++n) acc[m][n] = f32x4{0.f, 0.f, 0.f, 0.f};

#pragma unroll
    for (int c2 = 0; c2 < 2; ++c2) {
        const int oct = c2 * 4 + lg;
        bf16x8 a_h[2], a_l[2], b_h[2], b_l[2];
#pragma unroll
        for (int m = 0; m < 2; ++m) {
            int row = wr * 32 + m * 16 + lr;
            a_h[m] = ld_bf8(&sIh[swzR(row, oct)]);
            a_l[m] = ld_bf8(&sIl[swzR(row, oct)]);
            int col = wc * 32 + m * 16 + lr;
            b_h[m] = ld_bf8(&sJh[swzR(col, oct)]);
            b_l[m] = ld_bf8(&sJl[swzR(col, oct)]);
        }
#pragma unroll
        for (int m = 0; m < 2; ++m)
#pragma unroll
            for (int n = 0; n < 2; ++n) {
                acc[m][n] = mfma16(a_h[m], b_h[n], acc[m][n]);
                acc[m][n] = mfma16(a_h[m], b_l[n], acc[m][n]);
                acc[m][n] = mfma16(a_l[m], b_h[n], acc[m][n]);
            }
    }

    float* __restrict__ AEb = AE + (long)b * NN * NN;
#pragma unroll
    for (int m = 0; m < 2; ++m) {
        const int ib = i0 + wr * 32 + m * 16 + lg * 4;
#pragma unroll
        for (int n = 0; n < 2; ++n) {
            const int jc = j0 + wc * 32 + n * 16 + lr;
#pragma unroll
            for (int jj = 0; jj < 4; ++jj) {
                float v = fmaxf(acc[m][n][jj], 0.f);
                if (ib + jj == jc) v = 0.f;
                AEb[(long)(ib + jj) * NN + jc] = v;
            }
        }
    }
}

// ---------------------------------------------------------------------------
// LayerNorm over [N,D] + relu + mean/max pool. pre: fp32 col-major [64][512].
// h out: hi/lo bf16 planes row-major [512][64].
// ---------------------------------------------------------------------------
__global__ __launch_bounds__(256) void ln_pool(
    const float* __restrict__ pre, const float* __restrict__ gamma,
    const float* __restrict__ beta,
    unsigned short* __restrict__ hh, unsigned short* __restrict__ hl,
    float* __restrict__ zfeat, int zoff)
{
    const int b = blockIdx.x;
    const float* __restrict__ p = pre + (long)b * ND;
    const int t = threadIdx.x;

    float s = 0.f, s2 = 0.f;
    for (int i = t * 4; i < ND; i += 1024) {
        float4 v = *reinterpret_cast<const float4*>(p + i);
        s  += v.x + v.y + v.z + v.w;
        s2 += v.x * v.x + v.y * v.y + v.z * v.z + v.w * v.w;
    }
#pragma unroll
    for (int off = 32; off > 0; off >>= 1) {
        s  += __shfl_down(s, off, 64);
        s2 += __shfl_down(s2, off, 64);
    }
    __shared__ float red[8];
    if ((t & 63) == 0) { red[(t >> 6) * 2] = s; red[(t >> 6) * 2 + 1] = s2; }
    __syncthreads();
    __shared__ float mu_s, rstd_s;
    if (t == 0) {
        float ts  = red[0] + red[2] + red[4] + red[6];
        float ts2 = red[1] + red[3] + red[5] + red[7];
        float mu  = ts * (1.f / ND);
        float var = ts2 * (1.f / ND) - mu * mu;
        mu_s = mu; rstd_s = rsqrtf(var + 1e-5f);
    }
    __syncthreads();
    const float mu = mu_s, rstd = rstd_s;

    const int f4 = (t & 15) * 4, nt = t >> 4;
    float sum4[4] = {0.f, 0.f, 0.f, 0.f};
    float max4[4] = {0.f, 0.f, 0.f, 0.f};
    for (int n = nt; n < NN; n += 16) {
        float4 g4 = *reinterpret_cast<const float4*>(gamma + (long)n * DD + f4);
        float4 be = *reinterpret_cast<const float4*>(beta  + (long)n * DD + f4);
        float4 v;
        v.x = fmaxf((p[(long)(f4 + 0) * NN + n] - mu) * rstd * g4.x + be.x, 0.f);
        v.y = fmaxf((p[(long)(f4 + 1) * NN + n] - mu) * rstd * g4.y + be.y, 0.f);
        v.z = fmaxf((p[(long)(f4 + 2) * NN + n] - mu) * rstd * g4.z + be.z, 0.f);
        v.w = fmaxf((p[(long)(f4 + 3) * NN + n] - mu) * rstd * g4.w + be.w, 0.f);
        ushort4 h4, l4;
        cvt4(v, h4, l4);
        *reinterpret_cast<ushort4*>(hh + (long)b * ND + (long)n * DD + f4) = h4;
        *reinterpret_cast<ushort4*>(hl + (long)b * ND + (long)n * DD + f4) = l4;
        sum4[0] += v.x; sum4[1] += v.y; sum4[2] += v.z; sum4[3] += v.w;
        max4[0] = fmaxf(max4[0], v.x); max4[1] = fmaxf(max4[1], v.y);
        max4[2] = fmaxf(max4[2], v.z); max4[3] = fmaxf(max4[3], v.w);
    }
    __shared__ float rs[16][64], rm[16][64];
#pragma unroll
    for (int j = 0; j < 4; ++j) { rs[nt][f4 + j] = sum4[j]; rm[nt][f4 + j] = max4[j]; }
    __syncthreads();
    if (t < 64) {
        float ss = 0.f, mm = 0.f;
#pragma unroll
        for (int k = 0; k < 16; ++k) { ss += rs[k][t]; mm = fmaxf(mm, rm[k][t]); }
        zfeat[b * 256 + zoff + t]      = ss * (1.f / NN);
        zfeat[b * 256 + zoff + 64 + t] = mm;
    }
}

// ---------------------------------------------------------------------------
// W[z][kdim][64] fp32 -> fp32 transposed [z][64][kdim]
// ---------------------------------------------------------------------------
__global__ void transW(const float* __restrict__ W, float* __restrict__ Wt,
                       int kdim, int total)
{
    int o = blockIdx.x * 256 + threadIdx.x;
    if (o >= total) return;
    int per = 64 * kdim;
    int zz = o / per, r = o % per;
    int f = r / kdim, k = r % kdim;
    Wt[o] = W[((long)zz * kdim + k) * 64 + f];
}

// ---------------------------------------------------------------------------
// Tiny MLP heads (unchanged).
// ---------------------------------------------------------------------------
__global__ __launch_bounds__(64) void heads(
    const float* __restrict__ zfeat,
    const float* __restrict__ p1w, const float* __restrict__ p1b,
    const float* __restrict__ p2w, const float* __restrict__ p2b,
    const float* __restrict__ p3w, const float* __restrict__ p3b,
    const float* __restrict__ s1w, const float* __restrict__ s1b,
    const float* __restrict__ s2w, const float* __restrict__ s2b,
    const float* __restrict__ p4w, const float* __restrict__ p4b,
    float* __restrict__ outc, float* __restrict__ outs)
{
    const int b = blockIdx.x, t = threadIdx.x;
    __shared__ float zf[256], v1[64], v2[64], lg[2];
    for (int i = t; i < 256; i += 64) zf[i] = zfeat[b * 256 + i];
    __syncthreads();

    float a = p1b[t];
    for (int z = 0; z < 256; ++z) a = fmaf(zf[z], p1w[z * 64 + t], a);
    v1[t] = a >= 0.f ? a : 0.2f * a;
    __syncthreads();
    float a2 = p2b[t];
    for (int z = 0; z < 64; ++z) a2 = fmaf(v1[z], p2w[z * 64 + t], a2);
    v2[t] = a2 >= 0.f ? a2 : 0.2f * a2;
    __syncthreads();
    if (t < 4) {
        float a3 = p3b[t];
        for (int z = 0; z < 64; ++z) a3 = fmaf(v2[z], p3w[z * 4 + t], a3);
        outc[b * 4 + t] = 1.f / (1.f + expf(-a3));
    }
    __syncthreads();

    float c = s1b[t];
    for (int z = 0; z < 256; ++z) c = fmaf(zf[z], s1w[z * 64 + t], c);
    v1[t] = c >= 0.f ? c : 0.2f * c;
    __syncthreads();
    float c2 = s2b[t];
    for (int z = 0; z < 64; ++z) c2 = fmaf(v1[z], s2w[z * 64 + t], c2);
    v2[t] = c2 >= 0.f ? c2 : 0.2f * c2;
    __syncthreads();
    if (t < 2) {
        float d = p4b[t];
        for (int z = 0; z < 64; ++z) d = fmaf(v2[z], p4w[z * 2 + t], d);
        lg[t] = d;
    }
    __syncthreads();
    if (t < 2) {
        float m = fmaxf(lg[0], lg[1]);
        float lse = m + logf(expf(lg[0] - m) + expf(lg[1] - m));
        outs[b * 2 + t] = lg[t] - lse;
    }
}

// ---------------------------------------------------------------------------
// In-place Clenshaw over fp32 slots s0..s5 (col-major [b][64f][512n] in d_out).
// ---------------------------------------------------------------------------
template <int AM>
static void chebRun(const float* Afp, const unsigned short* Ahp, const unsigned short* Alp,
                    float* slots, const float* bias, int outf, float* Sout, float* X0f,
                    hipStream_t stream)
{
    const dim3 blk(256), grd(8, 64, 1);
    const long AB = (long)NN * NN;
    float* s0 = slots + 0 * BND;
    float* s1 = slots + 1 * BND;
    float* s2 = slots + 2 * BND;
    float* s3 = slots + 3 * BND;
    float* s4 = slots + 4 * BND;
    float* s5 = slots + 5 * BND;
    gemm_v7<AM, false, true, false, 0><<<grd, blk, 0, stream>>>(
        Afp, Ahp, Alp, NN, AB, s5, (long)ND, 0L, nullptr, s4, nullptr,
        2.f, 0.f, NN, s4, 0L);
    gemm_v7<AM, true, true, false, 0><<<grd, blk, 0, stream>>>(
        Afp, Ahp, Alp, NN, AB, s4, (long)ND, 0L, s5, s3, nullptr,
        2.f, -1.f, NN, s5, 0L);
    gemm_v7<AM, true, true, false, 0><<<grd, blk, 0, stream>>>(
        Afp, Ahp, Alp, NN, AB, s5, (long)ND, 0L, s4, s2, nullptr,
        2.f, -1.f, NN, s4, 0L);
    gemm_v7<AM, true, true, false, 0><<<grd, blk, 0, stream>>>(
        Afp, Ahp, Alp, NN, AB, s4, (long)ND, 0L, s5, s1, nullptr,
        2.f, -1.f, NN, s5, 0L);
    if (outf == 0)
        gemm_v7<AM, true, true, true, 0><<<grd, blk, 0, stream>>>(
            Afp, Ahp, Alp, NN, AB, s5, (long)ND, 0L, s4, s0, bias,
            1.f, -1.f, NN, Sout, 0L);
    else
        gemm_v7<AM, true, true, true, 1><<<grd, blk, 0, stream>>>(
            Afp, Ahp, Alp, NN, AB, s5, (long)ND, 0L, s4, s0, bias,
            1.f, -1.f, NN, X0f, 0L);
}

extern "C" void kernel_launch(void* const* d_in, const int* in_sizes, int n_in,
                              void* d_out, int out_size, void* d_ws, size_t ws_size,
                              hipStream_t stream)
{
    const float* A   = (const float*)d_in[0];
    const float* X   = (const float*)d_in[1];
    const float* W1  = (const float*)d_in[2];
    const float* b1v = (const float*)d_in[3];
    const float* W2  = (const float*)d_in[4];
    const float* b2v = (const float*)d_in[5];
    const float* W3  = (const float*)d_in[6];
    const float* b3v = (const float*)d_in[7];
    const float* g1  = (const float*)d_in[8];
    const float* bt1 = (const float*)d_in[9];
    const float* g2  = (const float*)d_in[10];
    const float* bt2 = (const float*)d_in[11];
    const float* p1w = (const float*)d_in[12];
    const float* p1b = (const float*)d_in[13];
    const float* p2w = (const float*)d_in[14];
    const float* p2b = (const float*)d_in[15];
    const float* p3w = (const float*)d_in[16];
    const float* p3b = (const float*)d_in[17];
    const float* s1w = (const float*)d_in[18];
    const float* s1b = (const float*)d_in[19];
    const float* s2w = (const float*)d_in[20];
    const float* s2b = (const float*)d_in[21];
    const float* p4w = (const float*)d_in[22];
    const float* p4b = (const float*)d_in[23];

    float* out   = (float*)d_out;
    float* slots = out;                      // 6 fp32 slots, 50.3 MB
    float* Sbuf  = out + 6 * BND;            // 8.4 MB pre-LN buffer
    float* outc  = out + (long)BB * NN * NN;
    float* outsc = outc + BB * 4;

    // ws layout: W1t | W2t | W3t | zfeat | hh,hl (X0f aliases) | Ahp,Alp | Xhp,Xlp
    float* wsf = (float*)d_ws;
    float* W1t = wsf;                                   // 196,608 floats
    float* W2t = wsf + 196608;                          // 24,576
    float* W3t = W2t + 24576;                           // 24,576
    float* zfeat = W3t + 24576;                         // 16,384
    unsigned short* hh = (unsigned short*)(zfeat + 16384);
    unsigned short* hl = hh + 2097152;
    float* X0f = (float*)hh;                            // aliases hh+hl (8.4 MB)
    unsigned short* Ahp = (unsigned short*)((char*)d_ws + 9437184);
    unsigned short* Alp = Ahp + 16777216;               // ends at byte 76,546,048
    unsigned short* Xhp = Alp + 16777216;
    unsigned short* Xlp = Xhp + 16777216;               // ends at byte 143,654,912

    const bool splitA = ws_size >= 76546048ULL;
    const bool splitX = ws_size >= 143654912ULL;

    const dim3 blk(256);
    const long AB = (long)NN * NN;

    transW<<<dim3((6 * NN * DD + 255) / 256), blk, 0, stream>>>(W1, W1t, NN, 6 * NN * DD);
    transW<<<dim3((6 * DD * DD + 255) / 256), blk, 0, stream>>>(W2, W2t, DD, 6 * DD * DD);
    transW<<<dim3((6 * DD * DD + 255) / 256), blk, 0, stream>>>(W3, W3t, DD, 6 * DD * DD);
    if (splitA)
        split_planes<<<dim3(2048), blk, 0, stream>>>(A, Ahp, Alp, (long)BB * NN * NN / 4);
    if (splitX)
        split_planes<<<dim3(2048), blk, 0, stream>>>(X, Xhp, Xlp, (long)BB * NN * NN / 4);

    auto cheb = [&](const float* bias, int outf) {
        if (splitA) chebRun<2>(nullptr, Ahp, Alp, slots, bias, outf, Sbuf, X0f, stream);
        else        chebRun<0>(A, nullptr, nullptr, slots, bias, outf, Sbuf, X0f, stream);
    };

    // ---- stage 1: Z_k = X @ W1[k] -> slots ----
    if (splitX)
        gemm_v7<2, false, false, false, 0><<<dim3(8, 64, 6), blk, 0, stream>>>(
            nullptr, Xhp, Xlp, NN, AB, W1t, 0L, (long)NN * DD,
            nullptr, nullptr, nullptr, 1.f, 0.f, NN, slots, BND);
    else
        gemm_v7<0, false, false, false, 0><<<dim3(8, 64, 6), blk, 0, stream>>>(
            X, nullptr, nullptr, NN, AB, W1t, 0L, (long)NN * DD,
            nullptr, nullptr, nullptr, 1.f, 0.f, NN, slots, BND);
    cheb(b1v, 0);
    ln_pool<<<dim3(64), blk, 0, stream>>>(Sbuf, g1, bt1, hh, hl, zfeat, 0);

    // ---- stage 2: Z_k = h @ W2[k] (h planes via gload_lds, K=64) ----
    gemm_v7<2, false, false, false, 0><<<dim3(8, 64, 6), blk, 0, stream>>>(
        nullptr, hh, hl, DD, (long)ND, W2t, 0L, (long)DD * DD,
        nullptr, nullptr, nullptr, 1.f, 0.f, DD, slots, BND);
    cheb(b2v, 0);
    ln_pool<<<dim3(64), blk, 0, stream>>>(Sbuf, g2, bt2, hh, hl, zfeat, 128);

    // ---- stage 3: Z_k = h @ W3[k]; Clenshaw -> X0 fp32 row-major (aliases h) ----
    gemm_v7<2, false, false, false, 0><<<dim3(8, 64, 6), blk, 0, stream>>>(
        nullptr, hh, hl, DD, (long)ND, W3t, 0L, (long)DD * DD,
        nullptr, nullptr, nullptr, 1.f, 0.f, DD, slots, BND);
    cheb(b3v, 1);

    // ---- AE = relu(X0 X0^T), zero diag ----
    outer_v7<<<dim3(8, 8, 64), blk, 0, stream>>>(X0f, out);

    // ---- heads ----
    heads<<<dim3(64), dim3(64), 0, stream>>>(
        zfeat, p1w, p1b, p2w, p2b, p3w, p3b, s1w, s1b, s2w, s2b, p4w, p4b, outc, outsc);
}